// Round 4
// baseline (175.010 us; speedup 1.0000x reference)
//
#include <hip/hip_runtime.h>
#include <stdint.h>

// CRF loss: S=32768, L=512. Chunked forward algorithm, exp-domain, fp8 MFMA.
// CH=16 -> 2048 fwd chunks + 2047 bwd chunks, 16 chunks (MFMA columns) per WG
// -> 128 fwd WGs + 128 bwd WGs = 256 WGs (one per CU).
// E' = 2*exp(T) as fp8 e4m3 MFMA A-fragments in VGPRs (128 VGPR/wave).
// Per step: C[512x16] = E' x P (v_mfma_f32_16x16x32_fp8_fp8), *exp(feat),
// per-column max renorm -> fp8 P' in LDS (B-fragment layout).
// m accumulates log(M) - ln448 - ln2 (-ln2 compensates E'=2E).
// logit rows are register-prefetched 2 steps ahead (hides ~900cyc HBM latency;
// no global stores in-loop so __syncthreads should not drain vmcnt).
// Tail fused: wave-per-chunk LSE + gold blocks + ticket last-block final.

#define S_LEN 32768
#define L 512
#define CH 16
#define NCF 2048            // fwd chunks (c = 0..2047)
#define WGF 128             // fwd WGs (16 cols each)
#define WGB 128             // bwd WGs (cols c = 1..2047 + 1 pad)
#define LN448 6.104793232f
#define LN2   0.6931471806f
#define NB_LSE  256         // tail: lse blocks (8 wave-tasks each)
#define NB_GOLD 64          // tail: gold blocks
#define NB_TAIL (NB_LSE + NB_GOLD)

// ws layout (bytes), total ~4.72 MB
#define OFF_EAF  0                       // 256 KB: A-frag fp8 of E'   (fwd)
#define OFF_EAB  (256*1024)              // 256 KB: A-frag fp8 of E'^T (bwd)
#define OFF_G    (512*1024)              // 2048*512 bf16 (2 MB)
#define OFF_H    (OFF_G + NCF*L*2)       // 2048*512 bf16 (2 MB, row 0 unused)
#define OFF_LSE  (OFF_H + NCF*L*2)       // [0..2047]=lse1, [2048..4095]=lse2, [4096]=lse(g_last)
#define OFF_GOLD (OFF_LSE + 4100*4)      // 64 f32
#define OFF_TKT  (OFF_GOLD + 64*4)      // 1 u32 ticket

typedef float v4f __attribute__((ext_vector_type(4)));

__device__ __forceinline__ float b2f(unsigned short u){
  return __uint_as_float(((unsigned)u) << 16);
}
__device__ __forceinline__ unsigned short f2b(float x){
  unsigned u = __float_as_uint(x);
  return (unsigned short)((u + 0x7fffu + ((u >> 16) & 1u)) >> 16);
}
__device__ __forceinline__ unsigned char to_fp8(float v){
  int u = __builtin_amdgcn_cvt_pk_fp8_f32(v, v, 0, false);
  return (unsigned char)(u & 0xff);
}

// ---------- prep: build A-fragment-swizzled fp8 E' and E'^T ----------
// long index = ((w*4+mt)*16+kt)*64 + lane ; byte r of that long =
//   Mat[m = w*64+mt*16+(lane&15)][k = kt*32+(lane>>4)*8+r]
extern "C" __global__ void crf_prep(const float* __restrict__ T,
                                    unsigned char* __restrict__ EAf,
                                    unsigned char* __restrict__ EAb,
                                    unsigned int* __restrict__ ticket){
  int tid = blockIdx.x*512 + threadIdx.x;        // 0..262143
  if (tid == 0) *ticket = 0;
  int r    = tid & 7;
  int lane = (tid >> 3) & 63;
  int kt   = (tid >> 9) & 15;
  int mtw  = tid >> 13;                          // w*4+mt, 0..31
  int j = (mtw >> 2)*64 + (mtw & 3)*16 + (lane & 15);
  int i = kt*32 + ((lane >> 4) << 3) + r;
  EAf[tid] = to_fp8(2.0f * __expf(T[j*L + i]));  // E'[j][i]
  EAb[tid] = to_fp8(2.0f * __expf(T[i*L + j]));  // E'^T[j][i] = E'[i][j]
}

// ---------- main chunk kernel ----------
extern "C" __global__ __launch_bounds__(512, 2)
void crf_chunks(const float* __restrict__ logit,
                const unsigned char* __restrict__ EAf,
                const unsigned char* __restrict__ EAb,
                unsigned short* __restrict__ G, unsigned short* __restrict__ H){
  // P in MFMA-B-fragment order: byte(n=col,k=row) =
  //   (k>>5)*512 + (((k>>3)&3)*16 + n)*8 + (k&7)
  __shared__ __align__(16) unsigned char Pl[2][8192];
  __shared__ float sPart[16][8];

  const int tid  = threadIdx.x;
  const int w    = tid >> 6;
  const int lane = tid & 63;
  const int quad = lane >> 4;
  const int cl   = lane & 15;                    // MFMA column = chunk slot
  const bool fwd = (blockIdx.x < WGF);
  const int  b   = fwd ? blockIdx.x : (blockIdx.x - WGF);
  const int  cg  = fwd ? (b*16 + cl) : (1 + b*16 + cl);
  const int  cgc = min(cg, NCF-1);
  const bool isc0 = fwd && (cg == 0);
  const int  jrow0 = w*64 + quad*4;              // C-layout base row (+mt*16)

  // ---- load E fragments into registers ----
  const long* EA = (const long*)(fwd ? EAf : EAb);
  long eA[4][16];
  #pragma unroll
  for (int mt = 0; mt < 4; ++mt)
    #pragma unroll
    for (int kt = 0; kt < 16; ++kt)
      eA[mt][kt] = EA[(((w<<2)+mt)<<4 | kt)*64 + lane];

  // ---- feature-row address helper (clamped for prefetch overrun) ----
  auto t_of = [&](int k)->int {
    if (fwd) return cgc*CH + min(k, CH-1);
    int kk = CH - 2 - k; if (kk < 0) kk = 0;
    return cgc*CH + kk;
  };

  // ---- prefetch logit rows for steps 0,1 ----
  float4 pf[2][4];
  #pragma unroll
  for (int kk = 0; kk < 2; ++kk) {
    const float* lp = logit + (size_t)t_of(kk)*L + jrow0;
    #pragma unroll
    for (int mt = 0; mt < 4; ++mt) pf[kk][mt] = *(const float4*)(lp + mt*16);
  }

  // ---- init v (true vector = vr * e^m elementwise, per column cl) ----
  float vr[4][4];
  if (fwd) {
    #pragma unroll
    for (int mt = 0; mt < 4; ++mt)
      #pragma unroll
      for (int r = 0; r < 4; ++r) vr[mt][r] = 1.0f;
  } else {
    const int t0 = cgc*CH + CH - 1;
    const float* lp = logit + (size_t)t0*L + jrow0;
    #pragma unroll
    for (int mt = 0; mt < 4; ++mt) {
      float4 x = *(const float4*)(lp + mt*16);
      vr[mt][0] = __expf(x.x); vr[mt][1] = __expf(x.y);
      vr[mt][2] = __expf(x.z); vr[mt][3] = __expf(x.w);
    }
  }
  float m = 0.0f;
  int par = 0;

  auto renorm_store = [&](int dst){
    float mx = vr[0][0];
    #pragma unroll
    for (int mt = 0; mt < 4; ++mt)
      #pragma unroll
      for (int r = 0; r < 4; ++r) mx = fmaxf(mx, vr[mt][r]);
    mx = fmaxf(mx, __shfl_xor(mx, 16));
    mx = fmaxf(mx, __shfl_xor(mx, 32));          // column max within wave
    if (quad == 0) sPart[cl][w] = mx;
    __syncthreads();
    float4 pa = *(const float4*)&sPart[cl][0];
    float4 pb = *(const float4*)&sPart[cl][4];
    float M = fmaxf(fmaxf(fmaxf(pa.x,pa.y),fmaxf(pa.z,pa.w)),
                    fmaxf(fmaxf(pb.x,pb.y),fmaxf(pb.z,pb.w)));
    float sc = 448.0f / M;
    #pragma unroll
    for (int mt = 0; mt < 4; ++mt) {
      int u = __builtin_amdgcn_cvt_pk_fp8_f32(vr[mt][0]*sc, vr[mt][1]*sc, 0, false);
      u     = __builtin_amdgcn_cvt_pk_fp8_f32(vr[mt][2]*sc, vr[mt][3]*sc, u, true);
      int r0 = jrow0 + mt*16;                    // k index of first of 4 rows
      *(int*)&Pl[dst][(r0 >> 5)*512 + ((((r0 >> 3) & 3)*16 + cl) << 3) + (r0 & 7)] = u;
    }
    m += __logf(M) - LN448;
    __syncthreads();
  };

  renorm_store(0);

  // ---- main loop: CH matvec steps ----
  for (int k = 0; k < CH; ++k) {
    const bool last = (k == CH-1);
    const bool useF = fwd || !last;

    // consume prefetched feature row -> exp factors (before MFMA; independent)
    float fex[4][4];
    #pragma unroll
    for (int mt = 0; mt < 4; ++mt) {
      float4 x = pf[k & 1][mt];
      fex[mt][0] = __expf(x.x); fex[mt][1] = __expf(x.y);
      fex[mt][2] = __expf(x.z); fex[mt][3] = __expf(x.w);
    }
    // issue prefetch for step k+2 (lands 2 barriers later)
    {
      const float* lp = logit + (size_t)t_of(k+2)*L + jrow0;
      #pragma unroll
      for (int mt = 0; mt < 4; ++mt) pf[k & 1][mt] = *(const float4*)(lp + mt*16);
    }

    v4f acc[4];
    #pragma unroll
    for (int mt = 0; mt < 4; ++mt) acc[mt] = (v4f){0.f,0.f,0.f,0.f};
    #pragma unroll
    for (int kt = 0; kt < 16; ++kt) {
      long bb = *(const long*)&Pl[par][kt*512 + lane*8];
      #pragma unroll
      for (int mt = 0; mt < 4; ++mt)
        acc[mt] = __builtin_amdgcn_mfma_f32_16x16x32_fp8_fp8(eA[mt][kt], bb, acc[mt], 0, 0, 0);
    }
    m -= LN2;                                    // compensate E' = 2E

    if (useF) {
      #pragma unroll
      for (int mt = 0; mt < 4; ++mt) {
        vr[mt][0] = acc[mt][0]*fex[mt][0]; vr[mt][1] = acc[mt][1]*fex[mt][1];
        vr[mt][2] = acc[mt][2]*fex[mt][2]; vr[mt][3] = acc[mt][3]*fex[mt][3];
        if (k == 0 && isc0) {          // chunk 0 exact anchor: alpha_0 = exp(feat_0)
          vr[mt][0] = fex[mt][0]; vr[mt][1] = fex[mt][1];
          vr[mt][2] = fex[mt][2]; vr[mt][3] = fex[mt][3];
        }
      }
      if (k == 0 && isc0) m = 0.0f;
    } else {
      #pragma unroll
      for (int mt = 0; mt < 4; ++mt)
        #pragma unroll
        for (int r = 0; r < 4; ++r) vr[mt][r] = acc[mt][r];
    }

    if (last) {
      if (cg <= NCF-1) {
        unsigned short* dst = (fwd ? G : H) + (size_t)cg*L + jrow0;
        #pragma unroll
        for (int mt = 0; mt < 4; ++mt) {
          ushort4 o;
          o.x = f2b(__logf(vr[mt][0]) + m); o.y = f2b(__logf(vr[mt][1]) + m);
          o.z = f2b(__logf(vr[mt][2]) + m); o.w = f2b(__logf(vr[mt][3]) + m);
          *(ushort4*)(dst + mt*16) = o;
        }
      }
    } else {
      renorm_store(par ^ 1);
      par ^= 1;
    }
  }
}

// ---------- block sum over 512 threads ----------
__device__ __forceinline__ float blockSum(float v, float* sred){
  #pragma unroll
  for (int off = 32; off >= 1; off >>= 1) v += __shfl_xor(v, off);
  int wid = threadIdx.x >> 6, lane = threadIdx.x & 63;
  if (lane == 0) sred[wid] = v;
  __syncthreads();
  if (threadIdx.x < 8) {
    float t = sred[threadIdx.x];
    t += __shfl_xor(t, 4); t += __shfl_xor(t, 2); t += __shfl_xor(t, 1);
    if (threadIdx.x == 0) sred[15] = t;
  }
  __syncthreads();
  float r = sred[15];
  __syncthreads();
  return r;
}

// ---------- fused tail: wave-per-chunk LSE + gold + ticketed final ----------
extern "C" __global__ __launch_bounds__(512)
void crf_tail(const float* __restrict__ logit, const int* __restrict__ labels,
              const float* __restrict__ T,
              const unsigned short* __restrict__ G,
              const unsigned short* __restrict__ H,
              float* __restrict__ lsebuf, float* __restrict__ part,
              unsigned int* __restrict__ ticket, float* __restrict__ out){
  __shared__ float sred[16];
  __shared__ bool amLast;
  const int tid = threadIdx.x, lane = tid & 63, wv = tid >> 6;
  const int b = blockIdx.x;

  if (b < NB_LSE) {
    const int task = b*8 + wv;                   // 0..2047
    if (task == 0) {
      // lse(g_last)
      const ushort4* gp = (const ushort4*)(G + (size_t)(NCF-1)*L + lane*8);
      ushort4 u0 = gp[0], u1 = gp[1];
      float v[8] = {b2f(u0.x),b2f(u0.y),b2f(u0.z),b2f(u0.w),
                    b2f(u1.x),b2f(u1.y),b2f(u1.z),b2f(u1.w)};
      float M = v[0];
      #pragma unroll
      for (int r = 1; r < 8; ++r) M = fmaxf(M, v[r]);
      #pragma unroll
      for (int off = 1; off <= 32; off <<= 1) M = fmaxf(M, __shfl_xor(M, off));
      float s = 0.f;
      #pragma unroll
      for (int r = 0; r < 8; ++r) s += __expf(v[r] - M);
      #pragma unroll
      for (int off = 1; off <= 32; off <<= 1) s += __shfl_xor(s, off);
      if (lane == 0) lsebuf[4096] = M + __logf(s);
    } else {
      const int c = task;                        // 1..2047
      const ushort4* hp = (const ushort4*)(H + (size_t)c*L + lane*8);
      const ushort4* gp = (const ushort4*)(G + (size_t)(c-1)*L + lane*8);
      ushort4 h0 = hp[0], h1 = hp[1], g0 = gp[0], g1 = gp[1];
      float hh[8] = {b2f(h0.x),b2f(h0.y),b2f(h0.z),b2f(h0.w),
                     b2f(h1.x),b2f(h1.y),b2f(h1.z),b2f(h1.w)};
      float aa[8] = {hh[0]+b2f(g0.x),hh[1]+b2f(g0.y),hh[2]+b2f(g0.z),hh[3]+b2f(g0.w),
                     hh[4]+b2f(g1.x),hh[5]+b2f(g1.y),hh[6]+b2f(g1.z),hh[7]+b2f(g1.w)};
      float Ma = aa[0], Mh = hh[0];
      #pragma unroll
      for (int r = 1; r < 8; ++r) { Ma = fmaxf(Ma, aa[r]); Mh = fmaxf(Mh, hh[r]); }
      #pragma unroll
      for (int off = 1; off <= 32; off <<= 1) {
        Ma = fmaxf(Ma, __shfl_xor(Ma, off));
        Mh = fmaxf(Mh, __shfl_xor(Mh, off));
      }
      float sa = 0.f, sh = 0.f;
      #pragma unroll
      for (int r = 0; r < 8; ++r) { sa += __expf(aa[r]-Ma); sh += __expf(hh[r]-Mh); }
      #pragma unroll
      for (int off = 1; off <= 32; off <<= 1) {
        sa += __shfl_xor(sa, off);
        sh += __shfl_xor(sh, off);
      }
      if (lane == 0) { lsebuf[c] = Ma + __logf(sa); lsebuf[2048 + c] = Mh + __logf(sh); }
    }
  } else {
    // gold path score: one timestep per thread
    const int t = (b - NB_LSE)*512 + tid;
    int yt = labels[t];
    float v = logit[(size_t)t*L + yt];
    if (t > 0) v += T[yt*L + labels[t-1]];
    float s = blockSum(v, sred);
    if (tid == 0) part[b - NB_LSE] = s;
  }

  // ---- ticket: last block computes the final scalar ----
  __syncthreads();
  if (tid == 0) {
    __threadfence();
    amLast = (atomicAdd(ticket, 1u) == (unsigned)(NB_TAIL - 1));
  }
  __syncthreads();
  if (amLast) {
    __threadfence();
    float acc = 0.f;
    #pragma unroll
    for (int c = tid; c < NCF; c += 512)
      if (c >= 1) acc += lsebuf[c] - lsebuf[2048 + c];
    if (tid < NB_GOLD) acc -= part[tid];
    float s = blockSum(acc, sred);
    if (tid == 0) out[0] = lsebuf[4096] + s;
  }
}

extern "C" void kernel_launch(void* const* d_in, const int* in_sizes, int n_in,
                              void* d_out, int out_size, void* d_ws, size_t ws_size,
                              hipStream_t stream){
  const float* logit = (const float*)d_in[0];
  const int* labels  = (const int*)d_in[1];
  const float* T     = (const float*)d_in[2];
  float* out = (float*)d_out;
  char* ws = (char*)d_ws;
  unsigned char* EAf = (unsigned char*)(ws + OFF_EAF);
  unsigned char* EAb = (unsigned char*)(ws + OFF_EAB);
  unsigned short* G  = (unsigned short*)(ws + OFF_G);
  unsigned short* H  = (unsigned short*)(ws + OFF_H);
  float* lsebuf = (float*)(ws + OFF_LSE);
  float* part   = (float*)(ws + OFF_GOLD);
  unsigned int* ticket = (unsigned int*)(ws + OFF_TKT);

  crf_prep  <<<512, 512, 0, stream>>>(T, EAf, EAb, ticket);
  crf_chunks<<<WGF + WGB, 512, 0, stream>>>(logit, EAf, EAb, G, H);
  crf_tail  <<<NB_TAIL, 512, 0, stream>>>(logit, labels, T, G, H,
                                          lsebuf, part, ticket, out);
}

// Round 5
// 155.572 us; speedup vs baseline: 1.1249x; 1.1249x over previous
//
#include <hip/hip_runtime.h>
#include <stdint.h>

// CRF loss: S=32768, L=512. Chunked forward algorithm, exp-domain, fp8 MFMA.
// CH=16 -> 2048 fwd chunks + 2047 bwd chunks, 16 chunks (MFMA columns) per WG
// -> 128 fwd WGs + 128 bwd WGs = 256 WGs (one per CU).
// E' = 2*exp(T) as fp8 e4m3 MFMA A-fragments in VGPRs.
// Per step: C[512x16] = E' x P (v_mfma_f32_16x16x32_fp8_fp8), *exp(feat),
// per-column max renorm -> fp8 P' in LDS (B-fragment layout).
// m accumulates log(M) - ln448 - ln2 (-ln2 compensates E'=2E).
// Round-4 lesson: pf[k&1] dynamic indexing -> scratch spill (105MB writes).
// Now: manual 2-step unroll, static pfA/pfB registers; in-loop barriers are
// raw s_waitcnt(lgkmcnt)+s_barrier so the logit prefetch stays in flight.
// Tail fused into chunks: pair tickets (fwd b + bwd b -> lse of chunks
// 16b+1..16b+16) + final ticket last-WG reduction. 2 kernels total.

#define S_LEN 32768
#define L 512
#define CH 16
#define NCF 2048            // fwd chunks (c = 0..2047)
#define WGF 128
#define WGB 128
#define NWG 256
#define LN448 6.104793232f
#define LN2   0.6931471806f

// ws layout (bytes), ~4.73 MB
#define OFF_EAF  0                       // 256 KB A-frag fp8 E'  (fwd)
#define OFF_EAB  (256*1024)              // 256 KB A-frag fp8 E'^T (bwd)
#define OFF_G    (512*1024)              // 2048*512 bf16
#define OFF_H    (OFF_G + NCF*L*2)       // 2048*512 bf16 (row 0 unused)
#define OFF_LSE  (OFF_H + NCF*L*2)       // [1..2047]=lse(h+g),[2048+c]=lse(h),[4096]=lse(g_last)
#define OFF_PART (OFF_LSE + 4100*4)      // 256 f32 gold partials
#define OFF_PTKT (OFF_PART + 256*4)      // 128 u32 pair tickets
#define OFF_FTKT (OFF_PTKT + 128*4)      // 1 u32 final ticket

// LDS-only barrier: wait DS ops, don't drain vmem (keeps prefetch in flight)
#define BAR_LDS() asm volatile("s_waitcnt lgkmcnt(0)\n\ts_barrier" ::: "memory")

typedef float v4f __attribute__((ext_vector_type(4)));

__device__ __forceinline__ float b2f(unsigned short u){
  return __uint_as_float(((unsigned)u) << 16);
}
__device__ __forceinline__ unsigned short f2b(float x){
  unsigned u = __float_as_uint(x);
  return (unsigned short)((u + 0x7fffu + ((u >> 16) & 1u)) >> 16);
}
__device__ __forceinline__ unsigned char to_fp8(float v){
  int u = __builtin_amdgcn_cvt_pk_fp8_f32(v, v, 0, false);
  return (unsigned char)(u & 0xff);
}

// ---------- prep: A-fragment-swizzled fp8 E'/E'^T + ticket zeroing ----------
// long index = ((w*4+mt)*16+kt)*64 + lane ; byte r of that long =
//   Mat[m = w*64+mt*16+(lane&15)][k = kt*32+(lane>>4)*8+r]
extern "C" __global__ void crf_prep(const float* __restrict__ T,
                                    unsigned char* __restrict__ EAf,
                                    unsigned char* __restrict__ EAb,
                                    unsigned int* __restrict__ ptkt,
                                    unsigned int* __restrict__ ftkt){
  int tid = blockIdx.x*512 + threadIdx.x;        // 0..262143
  if (tid < 129) { if (tid < 128) ptkt[tid] = 0u; else *ftkt = 0u; }
  int r    = tid & 7;
  int lane = (tid >> 3) & 63;
  int kt   = (tid >> 9) & 15;
  int mtw  = tid >> 13;                          // w*4+mt, 0..31
  int j = (mtw >> 2)*64 + (mtw & 3)*16 + (lane & 15);
  int i = kt*32 + ((lane >> 4) << 3) + r;
  EAf[tid] = to_fp8(2.0f * __expf(T[j*L + i]));  // E'[j][i]
  EAb[tid] = to_fp8(2.0f * __expf(T[i*L + j]));  // E'^T[j][i]
}

// ---------- block sum over 512 threads ----------
__device__ __forceinline__ float blockSum(float v, float* sred){
  #pragma unroll
  for (int off = 32; off >= 1; off >>= 1) v += __shfl_xor(v, off);
  int wid = threadIdx.x >> 6, lane = threadIdx.x & 63;
  if (lane == 0) sred[wid] = v;
  __syncthreads();
  if (threadIdx.x < 8) {
    float t = sred[threadIdx.x];
    t += __shfl_xor(t, 4); t += __shfl_xor(t, 2); t += __shfl_xor(t, 1);
    if (threadIdx.x == 0) sred[15] = t;
  }
  __syncthreads();
  float r = sred[15];
  __syncthreads();
  return r;
}

// ---------- main kernel: chunks + fused tail ----------
extern "C" __global__ __launch_bounds__(512, 2)
void crf_chunks(const float* __restrict__ logit,
                const unsigned char* __restrict__ EAf,
                const unsigned char* __restrict__ EAb,
                unsigned short* __restrict__ G, unsigned short* __restrict__ H,
                const int* __restrict__ labels, const float* __restrict__ T,
                float* __restrict__ part, float* __restrict__ lsebuf,
                unsigned int* __restrict__ ptkt, unsigned int* __restrict__ ftkt,
                float* __restrict__ out){
  // P in MFMA-B-fragment order: byte(n=col,k=row) =
  //   (k>>5)*512 + (((k>>3)&3)*16 + n)*8 + (k&7)
  __shared__ __align__(16) unsigned char Pl[2][8192];
  __shared__ float sPart[16][8];
  __shared__ float sred[16];
  __shared__ unsigned sOld, sOld2;

  const int tid  = threadIdx.x;
  const int w    = tid >> 6;
  const int lane = tid & 63;
  const int quad = lane >> 4;
  const int cl   = lane & 15;                    // MFMA column = chunk slot
  const bool fwd = (blockIdx.x < WGF);
  const int  b   = fwd ? blockIdx.x : (blockIdx.x - WGF);
  const int  cg  = fwd ? (b*16 + cl) : (1 + b*16 + cl);
  const int  cgc = min(cg, NCF-1);
  const bool isc0 = fwd && (cg == 0);
  const int  jrow0 = w*64 + quad*4;              // C-layout base row (+mt*16)

  // ---- E fragments in registers ----
  const long* EA = (const long*)(fwd ? EAf : EAb);
  long eA[4][16];
  #pragma unroll
  for (int mt = 0; mt < 4; ++mt)
    #pragma unroll
    for (int kt = 0; kt < 16; ++kt)
      eA[mt][kt] = EA[(((w<<2)+mt)<<4 | kt)*64 + lane];

  auto t_of = [&](int k)->int {
    if (fwd) return cgc*CH + min(k, CH-1);
    int kk = CH - 2 - k; if (kk < 0) kk = 0;
    return cgc*CH + kk;
  };

  // ---- prefetch steps 0,1 into static register arrays ----
  float4 pfA[4], pfB[4];
  { const float* lp = logit + (size_t)t_of(0)*L + jrow0;
    #pragma unroll
    for (int mt = 0; mt < 4; ++mt) pfA[mt] = *(const float4*)(lp + mt*16); }
  { const float* lp = logit + (size_t)t_of(1)*L + jrow0;
    #pragma unroll
    for (int mt = 0; mt < 4; ++mt) pfB[mt] = *(const float4*)(lp + mt*16); }

  // ---- init v ----
  float vr[4][4];
  if (fwd) {
    #pragma unroll
    for (int mt = 0; mt < 4; ++mt)
      #pragma unroll
      for (int r = 0; r < 4; ++r) vr[mt][r] = 1.0f;
  } else {
    const float* lp = logit + (size_t)(cgc*CH + CH - 1)*L + jrow0;
    #pragma unroll
    for (int mt = 0; mt < 4; ++mt) {
      float4 x = *(const float4*)(lp + mt*16);
      vr[mt][0] = __expf(x.x); vr[mt][1] = __expf(x.y);
      vr[mt][2] = __expf(x.z); vr[mt][3] = __expf(x.w);
    }
  }
  float m = 0.0f;

  auto renorm_store = [&](int dst){
    float mx = vr[0][0];
    #pragma unroll
    for (int mt = 0; mt < 4; ++mt)
      #pragma unroll
      for (int r = 0; r < 4; ++r) mx = fmaxf(mx, vr[mt][r]);
    mx = fmaxf(mx, __shfl_xor(mx, 16));
    mx = fmaxf(mx, __shfl_xor(mx, 32));          // column max within wave
    if (quad == 0) sPart[cl][w] = mx;
    BAR_LDS();
    float4 pa = *(const float4*)&sPart[cl][0];
    float4 pb = *(const float4*)&sPart[cl][4];
    float M = fmaxf(fmaxf(fmaxf(pa.x,pa.y),fmaxf(pa.z,pa.w)),
                    fmaxf(fmaxf(pb.x,pb.y),fmaxf(pb.z,pb.w)));
    float sc = 448.0f / M;
    #pragma unroll
    for (int mt = 0; mt < 4; ++mt) {
      int u = __builtin_amdgcn_cvt_pk_fp8_f32(vr[mt][0]*sc, vr[mt][1]*sc, 0, false);
      u     = __builtin_amdgcn_cvt_pk_fp8_f32(vr[mt][2]*sc, vr[mt][3]*sc, u, true);
      int r0 = jrow0 + mt*16;
      *(int*)&Pl[dst][(r0 >> 5)*512 + ((((r0 >> 3) & 3)*16 + cl) << 3) + (r0 & 7)] = u;
    }
    m += __logf(M) - LN448;
    BAR_LDS();
  };

  auto step = [&](int k, int rdBuf, int wrBuf, float4 (&pfc)[4]){
    const bool last = (k == CH-1);
    const bool useF = fwd || !last;
    float fex[4][4];
    #pragma unroll
    for (int mt = 0; mt < 4; ++mt) {
      float4 x = pfc[mt];
      fex[mt][0] = __expf(x.x); fex[mt][1] = __expf(x.y);
      fex[mt][2] = __expf(x.z); fex[mt][3] = __expf(x.w);
    }
    { const float* lp = logit + (size_t)t_of(k+2)*L + jrow0;   // prefetch k+2
      #pragma unroll
      for (int mt = 0; mt < 4; ++mt) pfc[mt] = *(const float4*)(lp + mt*16); }

    v4f acc[4];
    #pragma unroll
    for (int mt = 0; mt < 4; ++mt) acc[mt] = (v4f){0.f,0.f,0.f,0.f};
    #pragma unroll
    for (int kt = 0; kt < 16; ++kt) {
      long bb = *(const long*)&Pl[rdBuf][kt*512 + lane*8];
      #pragma unroll
      for (int mt = 0; mt < 4; ++mt)
        acc[mt] = __builtin_amdgcn_mfma_f32_16x16x32_fp8_fp8(eA[mt][kt], bb, acc[mt], 0, 0, 0);
    }
    m -= LN2;                                    // compensate E' = 2E

    if (useF) {
      #pragma unroll
      for (int mt = 0; mt < 4; ++mt) {
        vr[mt][0] = acc[mt][0]*fex[mt][0]; vr[mt][1] = acc[mt][1]*fex[mt][1];
        vr[mt][2] = acc[mt][2]*fex[mt][2]; vr[mt][3] = acc[mt][3]*fex[mt][3];
        if (k == 0 && isc0) {                    // exact anchor: alpha_0
          vr[mt][0] = fex[mt][0]; vr[mt][1] = fex[mt][1];
          vr[mt][2] = fex[mt][2]; vr[mt][3] = fex[mt][3];
        }
      }
      if (k == 0 && isc0) m = 0.0f;
    } else {
      #pragma unroll
      for (int mt = 0; mt < 4; ++mt)
        #pragma unroll
        for (int r = 0; r < 4; ++r) vr[mt][r] = acc[mt][r];
    }

    if (last) {
      if (cg <= NCF-1) {
        unsigned short* dst = (fwd ? G : H) + (size_t)cg*L + jrow0;
        #pragma unroll
        for (int mt = 0; mt < 4; ++mt) {
          ushort4 o;
          o.x = f2b(__logf(vr[mt][0]) + m); o.y = f2b(__logf(vr[mt][1]) + m);
          o.z = f2b(__logf(vr[mt][2]) + m); o.w = f2b(__logf(vr[mt][3]) + m);
          *(ushort4*)(dst + mt*16) = o;
        }
      }
    } else {
      renorm_store(wrBuf);
    }
  };

  renorm_store(0);
  for (int kk = 0; kk < CH; kk += 2) {   // parity static: even reads 0, odd reads 1
    step(kk,     0, 1, pfA);
    step(kk + 1, 1, 0, pfB);
  }

  // ---- gold partial: 128 timesteps per WG ----
  {
    float gv = 0.f;
    if (tid < 128) {
      int t = blockIdx.x*128 + tid;
      int yt = labels[t];
      gv = logit[(size_t)t*L + yt];
      if (t > 0) gv += T[yt*L + labels[t-1]];
    }
    float s = blockSum(gv, sred);
    if (tid == 0) part[blockIdx.x] = s;
  }

  // ---- pair rendezvous: second arriver computes lse for chunks 16b+1..16b+16 ----
  __syncthreads();                               // drain all prior global stores
  if (tid == 0) { __threadfence(); sOld = atomicAdd(&ptkt[b], 1u); }
  __syncthreads();
  if (sOld == 1u) {
    __threadfence();                             // acquire partner's G/H
    const int wv = w;
    #pragma unroll
    for (int q = 0; q < 2; ++q) {
      int idx = wv*2 + q;                        // 0..15
      int c = b*16 + 1 + idx;                    // 1..2048
      if (c <= NCF-1) {
        const ushort4* hp = (const ushort4*)(H + (size_t)c*L + lane*8);
        const ushort4* gp = (const ushort4*)(G + (size_t)(c-1)*L + lane*8);
        ushort4 h0 = hp[0], h1 = hp[1], g0 = gp[0], g1 = gp[1];
        float hh[8] = {b2f(h0.x),b2f(h0.y),b2f(h0.z),b2f(h0.w),
                       b2f(h1.x),b2f(h1.y),b2f(h1.z),b2f(h1.w)};
        float aa[8] = {hh[0]+b2f(g0.x),hh[1]+b2f(g0.y),hh[2]+b2f(g0.z),hh[3]+b2f(g0.w),
                       hh[4]+b2f(g1.x),hh[5]+b2f(g1.y),hh[6]+b2f(g1.z),hh[7]+b2f(g1.w)};
        float Ma = aa[0], Mh = hh[0];
        #pragma unroll
        for (int r = 1; r < 8; ++r) { Ma = fmaxf(Ma, aa[r]); Mh = fmaxf(Mh, hh[r]); }
        #pragma unroll
        for (int off = 1; off <= 32; off <<= 1) {
          Ma = fmaxf(Ma, __shfl_xor(Ma, off));
          Mh = fmaxf(Mh, __shfl_xor(Mh, off));
        }
        float sa = 0.f, sh = 0.f;
        #pragma unroll
        for (int r = 0; r < 8; ++r) { sa += __expf(aa[r]-Ma); sh += __expf(hh[r]-Mh); }
        #pragma unroll
        for (int off = 1; off <= 32; off <<= 1) {
          sa += __shfl_xor(sa, off);
          sh += __shfl_xor(sh, off);
        }
        if (lane == 0) { lsebuf[c] = Ma + __logf(sa); lsebuf[NCF + c] = Mh + __logf(sh); }
      } else {                                   // b==127,idx==15: lse(g_last)
        const ushort4* gp = (const ushort4*)(G + (size_t)(NCF-1)*L + lane*8);
        ushort4 u0 = gp[0], u1 = gp[1];
        float v[8] = {b2f(u0.x),b2f(u0.y),b2f(u0.z),b2f(u0.w),
                      b2f(u1.x),b2f(u1.y),b2f(u1.z),b2f(u1.w)};
        float M = v[0];
        #pragma unroll
        for (int r = 1; r < 8; ++r) M = fmaxf(M, v[r]);
        #pragma unroll
        for (int off = 1; off <= 32; off <<= 1) M = fmaxf(M, __shfl_xor(M, off));
        float s = 0.f;
        #pragma unroll
        for (int r = 0; r < 8; ++r) s += __expf(v[r] - M);
        #pragma unroll
        for (int off = 1; off <= 32; off <<= 1) s += __shfl_xor(s, off);
        if (lane == 0) lsebuf[2*NCF] = M + __logf(s);
      }
    }
  }

  // ---- final ticket: 256th WG reduces everything ----
  __syncthreads();                               // drain lse stores
  if (tid == 0) { __threadfence(); sOld2 = atomicAdd(ftkt, 1u); }
  __syncthreads();
  if (sOld2 == (unsigned)(NWG - 1)) {
    __threadfence();
    float acc = 0.f;
    for (int c = tid; c < NCF; c += 512)
      if (c >= 1) acc += lsebuf[c] - lsebuf[NCF + c];
    if (tid < NWG) acc -= part[tid];
    float s = blockSum(acc, sred);
    if (tid == 0) out[0] = lsebuf[2*NCF] + s;
  }
}

extern "C" void kernel_launch(void* const* d_in, const int* in_sizes, int n_in,
                              void* d_out, int out_size, void* d_ws, size_t ws_size,
                              hipStream_t stream){
  const float* logit = (const float*)d_in[0];
  const int* labels  = (const int*)d_in[1];
  const float* T     = (const float*)d_in[2];
  float* out = (float*)d_out;
  char* ws = (char*)d_ws;
  unsigned char* EAf = (unsigned char*)(ws + OFF_EAF);
  unsigned char* EAb = (unsigned char*)(ws + OFF_EAB);
  unsigned short* G  = (unsigned short*)(ws + OFF_G);
  unsigned short* H  = (unsigned short*)(ws + OFF_H);
  float* lsebuf = (float*)(ws + OFF_LSE);
  float* part   = (float*)(ws + OFF_PART);
  unsigned int* ptkt = (unsigned int*)(ws + OFF_PTKT);
  unsigned int* ftkt = (unsigned int*)(ws + OFF_FTKT);

  crf_prep  <<<512, 512, 0, stream>>>(T, EAf, EAb, ptkt, ftkt);
  crf_chunks<<<NWG, 512, 0, stream>>>(logit, EAf, EAb, G, H, labels, T,
                                      part, lsebuf, ptkt, ftkt, out);
}